// Round 11
// baseline (360.998 us; speedup 1.0000x reference)
//
#include <hip/hip_runtime.h>
#include <cstdint>
#include <cmath>

#define NROWS 8192
#define KDIM  512            // elements; also bytes/row in fp8
#define NTILES 3104          // 2048 neg + 1056 pos (upper-tri)
#define PBLOCKS 512          // persistent blocks, 2 per CU

typedef int    i32x4  __attribute__((ext_vector_type(4)));
typedef int    i32x8  __attribute__((ext_vector_type(8)));
typedef float  f32x16 __attribute__((ext_vector_type(16)));
typedef unsigned char u8;

#define AS1(p) ((const __attribute__((address_space(1))) void*)(p))
#define AS3(p) ((__attribute__((address_space(3))) void*)(p))

// --- Kernel 1: row L2-normalize fp32 -> fp8 e4m3 (OCP, HW cvt), one wave/row.
// zi rows [0,8192), zj rows [8192,16384). Also zeroes the 128 accumulator slots.
__global__ __launch_bounds__(256) void nrm_kernel(const float* __restrict__ zi,
                                                  const float* __restrict__ zj,
                                                  u8* __restrict__ out,
                                                  double* __restrict__ acc) {
    if (blockIdx.x == 0 && threadIdx.x < 128) acc[threadIdx.x] = 0.0;
    const int wave = threadIdx.x >> 6;
    const int lane = threadIdx.x & 63;
    const int row  = blockIdx.x * 4 + wave;            // 0..16383
    const float* src = (row < NROWS) ? zi + (size_t)row * KDIM
                                     : zj + (size_t)(row - NROWS) * KDIM;
    float4 a = ((const float4*)src)[lane];
    float4 b = ((const float4*)src)[lane + 64];
    float ss = a.x*a.x + a.y*a.y + a.z*a.z + a.w*a.w
             + b.x*b.x + b.y*b.y + b.z*b.z + b.w*b.w;
    #pragma unroll
    for (int off = 32; off >= 1; off >>= 1) ss += __shfl_xor(ss, off, 64);
    const float inv = 1.0f / fmaxf(sqrtf(ss), 1e-12f);
    int p0 = 0, p1 = 0;
    p0 = __builtin_amdgcn_cvt_pk_fp8_f32(a.x * inv, a.y * inv, p0, false);
    p0 = __builtin_amdgcn_cvt_pk_fp8_f32(a.z * inv, a.w * inv, p0, true);
    p1 = __builtin_amdgcn_cvt_pk_fp8_f32(b.x * inv, b.y * inv, p1, false);
    p1 = __builtin_amdgcn_cvt_pk_fp8_f32(b.z * inv, b.w * inv, p1, true);
    int* dst = (int*)(out + (size_t)row * KDIM);
    dst[lane]      = p0;
    dst[lane + 64] = p1;
}

// --- Kernel 2: fused MX-fp8 A*B^T -> exp(10*dot) -> global sum. PERSISTENT.
// R22: 512 persistent blocks (2/CU), each walks ~6 tiles of the 3104-entry
// work list, with the NEXT tile's first BK=128 stage issued BEFORE the
// epilogue so the ~1300 cyc of exp2/reduce VALU covers the prologue load
// latency that every block previously paid cold. Rationale: R11-R21 proved
// no pipe is saturated (MFMA 27%, LDS port ~51%) and MFMA-busy is a constant
// ~21 us (ideal work); the residue is per-tile fill/drain — K is only 4
// BK-iters deep, so ~12 sequential blocks/CU each paid an exposed L2 round
// trip at k0=0 plus epilogue serialization. Persistent + prefetch-next
// amortizes that 12x, and deletes the 992 dead early-return dispatches.
// R21 closure: SQ_LDS_BANK_CONFLICT = 4 x ds_read_b128 count is INTRINSIC
// to the b128 width (bit-identical under a provably different bank
// permutation) — swizzle space is closed; reverted to the R11/R18 formulas
// (longest-verified, absmax 0 throughout).
// Work list: ids [0,2048) = neg: bx = 64 + (id&63), by = id>>6.
// ids [2048,3104) = pos: p = id-2048; by = max{y : cum(y) <= p},
// cum(y) = y*(65-y); o = p - cum(by); bx = 2*by + o. Diag pair o<2 skips
// rr==cc; o>=2 weight 2 (stands in for skipped mirror).
// Lessons held: no fused finalize (R12/R13: agent-acquire = per-block L2
// invalidate = 2x), no sched_barrier pins (m141/R12), no runtime-indexed
// LDS buffers (R12), 2 blocks/CU (R16/R19/R20), plain relaxed atomicAdd.
__global__ __launch_bounds__(256, 2) void gemm_exp_reduce(const u8* __restrict__ A,
                                                          const u8* __restrict__ B,
                                                          double* __restrict__ acc) {
    __shared__ u8 lA[2][256 * 64];   // 2 k-halves x 16 KB (8 regions of 32r x 64B)
    __shared__ u8 lB[2][128 * 64];   // 2 k-halves x 8 KB  (4 regions)
    __shared__ float red[4];

    const int tid  = threadIdx.x;
    const int lane = tid & 63;
    const int wave = tid >> 6;
    const int wm   = (wave >> 1) * 128;
    const int wn   = (wave & 1) * 64;

    // staging constants (verified R2-R21): 16-row chunks of 1024 B per k-half.
    // A: wave stages chunks wave*4..+3; B: wave*2..+1.
    // lane: row-in-chunk lane>>2, 16B-col bsw = (lane&3)^((lane>>3)&3).
    const int bsw  = (lane & 3) ^ ((lane >> 3) & 3);
    const int rowo = (lane >> 2);
    const int ldsA = wave * 4096 + lane * 16;
    const int ldsB = wave * 2048 + lane * 16;

    // fragment read: lane row r=lane&31, k-half q=lane>>5 (chunks 2q,2q+1);
    // swizzled slot p = r*4 + ((2q) ^ ((r>>1)&3)); partner chunk at ^16.
    const int r_  = lane & 31;
    const int q_  = lane >> 5;
    const int p16 = (r_ * 4 + ((2 * q_) ^ ((r_ >> 1) & 3))) * 16;
    const int aT0 = (wave >> 1) * 4;   // A regions aT0..aT0+3 (128 rows)
    const int bT0 = (wave & 1) * 2;    // B regions bT0..bT0+1 (64 rows)

    // id -> (bx, by). Uniform across the block (scalar).
    auto mapTile = [&](int id, int& bx, int& by) {
        if (id < 2048) { by = id >> 6; bx = 64 + (id & 63); }
        else {
            int p = id - 2048;
            int g = (int)((65.0f - sqrtf(4225.0f - 4.0f * (float)p)) * 0.5f);
            g = g < 0 ? 0 : (g > 31 ? 31 : g);
            while (g < 31 && (g + 1) * (65 - (g + 1)) <= p) ++g;
            while (g > 0 && g * (65 - g) > p) --g;
            by = g; bx = 2 * g + (p - g * (65 - g));
        }
    };

    auto stage = [&](const u8* gA0, const u8* gB0, int k0) {
        #pragma unroll
        for (int h = 0; h < 2; ++h) {
            const size_t kb = (size_t)k0 + h * 64;
            #pragma unroll
            for (int c = 0; c < 4; ++c)
                __builtin_amdgcn_global_load_lds(AS1(gA0 + kb + (size_t)c * 16 * KDIM),
                                                 AS3(&lA[h][ldsA + c * 1024]), 16, 0, 0);
            #pragma unroll
            for (int c = 0; c < 2; ++c)
                __builtin_amdgcn_global_load_lds(AS1(gB0 + kb + (size_t)c * 16 * KDIM),
                                                 AS3(&lB[h][ldsB + c * 1024]), 16, 0, 0);
        }
    };

    f32x16 accf[4][2];
    #pragma unroll
    for (int i = 0; i < 4; ++i)
        #pragma unroll
        for (int j = 0; j < 2; ++j)
            #pragma unroll
            for (int r = 0; r < 16; ++r)
                accf[i][j][r] = 0.f;

    int id, bx, by;
    id = blockIdx.x;
    mapTile(id, bx, by);
    const u8* gA0 = A + (size_t)(by * 256 + wave * 64 + rowo) * KDIM + bsw * 16;
    const u8* gB0 = B + (size_t)(bx * 128 + wave * 32 + rowo) * KDIM + bsw * 16;
    stage(gA0, gB0, 0);                    // prologue prefetch of tile 0, k0=0

    const float LOG2E10 = 14.4269504088896341f;

    while (true) {
        const bool pos = (bx < 64);
        const int  m0  = by * 256;
        const int  n0  = bx * 128;

        for (int k0 = 0; k0 < KDIM; k0 += 128) {   // BK=128: 4 iters
            if (k0) {
                __syncthreads();                   // prev reads done before overwrite
                stage(gA0, gB0, k0);
            }
            __syncthreads();                       // vmcnt drain: both halves ready
            #pragma unroll
            for (int h = 0; h < 2; ++h) {          // 16 MFMAs between barrier pairs
                i32x8 af[4], bfr[2];
                #pragma unroll
                for (int mi = 0; mi < 4; ++mi) {
                    const int off = (aT0 + mi) * 2048 + p16;
                    *(i32x4*)&af[mi]       = *(const i32x4*)&lA[h][off];
                    *((i32x4*)&af[mi] + 1) = *(const i32x4*)&lA[h][off ^ 16];
                }
                #pragma unroll
                for (int ni = 0; ni < 2; ++ni) {
                    const int off = (bT0 + ni) * 2048 + p16;
                    *(i32x4*)&bfr[ni]       = *(const i32x4*)&lB[h][off];
                    *((i32x4*)&bfr[ni] + 1) = *(const i32x4*)&lB[h][off ^ 16];
                }
                #pragma unroll
                for (int mi = 0; mi < 4; ++mi)
                    #pragma unroll
                    for (int ni = 0; ni < 2; ++ni)
                        accf[mi][ni] = __builtin_amdgcn_mfma_scale_f32_32x32x64_f8f6f4(
                            af[mi], bfr[ni], accf[mi][ni],
                            0, 0,                 // cbsz=fp8(e4m3), blgp=fp8(e4m3)
                            0, 0x7f7f7f7f,        // scale_a: every byte = 2^0
                            0, 0x7f7f7f7f);       // scale_b
            }
        }

        // Prefetch NEXT tile's k0=0 BEFORE the epilogue: its load latency is
        // covered by ~1300 cyc of exp2/reduce VALU below (the epilogue's own
        // __syncthreads drains it at the end, by which time it has landed).
        const int nid = id + PBLOCKS;
        const bool more = (nid < NTILES);
        __syncthreads();                           // last MFMA reads done
        if (more) {
            int nbx, nby;
            mapTile(nid, nbx, nby);
            gA0 = A + (size_t)(nby * 256 + wave * 64 + rowo) * KDIM + bsw * 16;
            gB0 = B + (size_t)(nbx * 128 + wave * 32 + rowo) * KDIM + bsw * 16;
            stage(gA0, gB0, 0);
            id = nid; bx = nbx; by = nby;          // loop state for next iter
        }

        // epilogue: exp(10*d) = exp2(d*10/ln2); near-diag pos blocks skip rr==cc
        const bool diag = pos && ((n0 >> 8) == (m0 >> 8));   // bx>>1 == by
        float part = 0.f;
        if (diag) {
            #pragma unroll
            for (int mi = 0; mi < 4; ++mi)
                #pragma unroll
                for (int ni = 0; ni < 2; ++ni)
                    #pragma unroll
                    for (int r = 0; r < 16; ++r) {
                        // C/D 32x32: col=lane&31, row=(r&3)+8*(r>>2)+4*(lane>>5)
                        int rr = m0 + wm + mi * 32 + ((r & 3) + 8 * (r >> 2) + 4 * q_);
                        int cc = n0 + wn + ni * 32 + r_;
                        if (rr != cc) part += exp2f(accf[mi][ni][r] * LOG2E10);
                    }
        } else {
            #pragma unroll
            for (int mi = 0; mi < 4; ++mi)
                #pragma unroll
                for (int ni = 0; ni < 2; ++ni)
                    #pragma unroll
                    for (int r = 0; r < 16; ++r)
                        part += exp2f(accf[mi][ni][r] * LOG2E10);
        }
        #pragma unroll
        for (int i = 0; i < 4; ++i)
            #pragma unroll
            for (int j = 0; j < 2; ++j)
                #pragma unroll
                for (int r = 0; r < 16; ++r)
                    accf[i][j][r] = 0.f;           // reset for next tile

        #pragma unroll
        for (int off = 32; off >= 1; off >>= 1) part += __shfl_xor(part, off, 64);
        if (lane == 0) red[wave] = part;
        __syncthreads();                           // also drains the prefetch
        if (tid == 0) {
            double s = (double)red[0] + (double)red[1] + (double)red[2] + (double)red[3];
            // pos tile strictly above the diagonal pair: counts for its mirror too
            if (pos && !diag) s *= 2.0;
            const unsigned bxu = (unsigned)(n0 >> 7), byu = (unsigned)(m0 >> 8);
            atomicAdd(&acc[(pos ? 0 : 64) + ((bxu * 7 + byu) & 63)], s);
        }
        __syncthreads();                           // red[] reusable next tile

        if (!more) break;
    }
}

// --- Kernel 3: loss = log1p(neg/pos), pos += exact diagonal 8192*e^10.
// 128 threads, one global load each; LDS reduce then scalar finish.
__global__ __launch_bounds__(128) void finalize(const double* __restrict__ acc,
                                                float* __restrict__ out) {
    __shared__ double sp[128];
    const int t = threadIdx.x;
    sp[t] = acc[t];
    __syncthreads();
    if (t == 0) {
        double p = 0.0, n = 0.0;
        #pragma unroll
        for (int i = 0; i < 64; ++i) { p += sp[i]; n += sp[64 + i]; }
        p += 8192.0 * exp(10.0);
        out[0] = (float)log1p(n / p);
    }
}

extern "C" void kernel_launch(void* const* d_in, const int* in_sizes, int n_in,
                              void* d_out, int out_size, void* d_ws, size_t ws_size,
                              hipStream_t stream) {
    const float* zi = (const float*)d_in[0];
    const float* zj = (const float*)d_in[1];
    u8* nrm = (u8*)d_ws;                                      // [16384][512] fp8 = 8 MB
    double* acc = (double*)((char*)d_ws + (size_t)16384 * 512);

    nrm_kernel<<<4096, 256, 0, stream>>>(zi, zj, nrm, acc);
    gemm_exp_reduce<<<PBLOCKS, 256, 0, stream>>>(nrm, nrm, acc);
    finalize<<<1, 128, 0, stream>>>(acc, (float*)d_out);
}

// Round 13
// 350.233 us; speedup vs baseline: 1.0307x; 1.0307x over previous
//
#include <hip/hip_runtime.h>
#include <cstdint>
#include <cmath>

#define NROWS 8192
#define KDIM  512            // elements; also bytes/row in fp8
#define NTILES 3104          // 2048 neg + 1056 pos (upper-tri incl. diag pair)
#define PBLOCKS 512          // persistent blocks, 2 per CU

typedef int    i32x4  __attribute__((ext_vector_type(4)));
typedef int    i32x8  __attribute__((ext_vector_type(8)));
typedef float  f32x16 __attribute__((ext_vector_type(16)));
typedef unsigned char u8;

#define AS1(p) ((const __attribute__((address_space(1))) void*)(p))
#define AS3(p) ((__attribute__((address_space(3))) void*)(p))

// --- Kernel 1: row L2-normalize fp32 -> fp8 e4m3 (OCP, HW cvt), one wave/row.
// zi rows [0,8192), zj rows [8192,16384). Also zeroes the 128 accumulator slots.
__global__ __launch_bounds__(256) void nrm_kernel(const float* __restrict__ zi,
                                                  const float* __restrict__ zj,
                                                  u8* __restrict__ out,
                                                  double* __restrict__ acc) {
    if (blockIdx.x == 0 && threadIdx.x < 128) acc[threadIdx.x] = 0.0;
    const int wave = threadIdx.x >> 6;
    const int lane = threadIdx.x & 63;
    const int row  = blockIdx.x * 4 + wave;            // 0..16383
    const float* src = (row < NROWS) ? zi + (size_t)row * KDIM
                                     : zj + (size_t)(row - NROWS) * KDIM;
    float4 a = ((const float4*)src)[lane];
    float4 b = ((const float4*)src)[lane + 64];
    float ss = a.x*a.x + a.y*a.y + a.z*a.z + a.w*a.w
             + b.x*b.x + b.y*b.y + b.z*b.z + b.w*b.w;
    #pragma unroll
    for (int off = 32; off >= 1; off >>= 1) ss += __shfl_xor(ss, off, 64);
    const float inv = 1.0f / fmaxf(sqrtf(ss), 1e-12f);
    int p0 = 0, p1 = 0;
    p0 = __builtin_amdgcn_cvt_pk_fp8_f32(a.x * inv, a.y * inv, p0, false);
    p0 = __builtin_amdgcn_cvt_pk_fp8_f32(a.z * inv, a.w * inv, p0, true);
    p1 = __builtin_amdgcn_cvt_pk_fp8_f32(b.x * inv, b.y * inv, p1, false);
    p1 = __builtin_amdgcn_cvt_pk_fp8_f32(b.z * inv, b.w * inv, p1, true);
    int* dst = (int*)(out + (size_t)row * KDIM);
    dst[lane]      = p0;
    dst[lane + 64] = p1;
}

// --- Kernel 2: fused MX-fp8 A*B^T -> exp(10*dot) -> global sum. PERSISTENT.
// R23 = R22's design (absmax 0 — mapping/weights/prefetch logic verified)
// with the SPILL removed. R22 post-mortem: VGPR hit the (256,2) cap (128 VGPR
// + 128 AGPR acc) -> accumulator spilled -> 1.1 GB scratch traffic (FETCH
// 437 MB / WRITE 643 MB) -> 3.5x regression. The fill/drain theory was never
// tested. Register fixes here:
//   * accf declared INSIDE the tile loop, zeroed at the TOP: dead between
//     the epilogue's last read and the next zero (R22 kept it live across
//     the while back-edge via the post-epilogue reset).
//   * no carried pointers: stage(bx,by,k0) recomputes addresses per call
//     (transient); only uniform id/bx/by cross the epilogue.
//   * mapTile unchanged (verified), transient temps only.
// Why persistence: K=512 = only 8 K-steps/tile -> per-tile fill (exposed L2
// round trip at k0=0) + drain (epilogue serialization) is the residue the
// guide's shape curve (m102: N=512 -> 18 TF) attributes to shallow dims;
// prefetching next tile's k0=0 before the epilogue hides it under ~1300 cyc
// of exp2/reduce. Work list (R22-verified): ids [0,2048) neg: bx=64+(id&63)
// (fixed per block since 512===0 mod 64 -> B-panel L2 reuse + XCD affinity),
// by=id>>6 (stride-8 walk). ids [2048,3104) pos: p=id-2048, by = max{y:
// y*(65-y) <= p}, o=p-by*(65-y), bx=2by+o; o<2 = diag pair (skip rr==cc),
// o>=2 weight 2. K-loop/staging/swizzle byte-identical to R18 (absmax 0
// throughout). Lessons held: no fused finalize (R12/R13 L2-invalidate), no
// sched_barrier pins (m141), no runtime-indexed LDS bufs, 2 blocks/CU.
// R24 note: R23's first submission died to a container-acquisition infra
// failure (no compile error, no counters). Kernel audited for hang/crash
// risk (no inter-block deps, uniform barriers, bounded loops, in-bounds
// addresses) and resubmitted unchanged.
__global__ __launch_bounds__(256, 2) void gemm_exp_reduce(const u8* __restrict__ A,
                                                          const u8* __restrict__ B,
                                                          double* __restrict__ acc) {
    __shared__ u8 lA[2][256 * 64];   // 2 k-halves x 16 KB (8 regions of 32r x 64B)
    __shared__ u8 lB[2][128 * 64];   // 2 k-halves x 8 KB  (4 regions)
    __shared__ float red[4];

    const int tid  = threadIdx.x;
    const int lane = tid & 63;
    const int wave = tid >> 6;
    const int wm   = (wave >> 1) * 128;
    const int wn   = (wave & 1) * 64;

    // staging constants (verified R2-R22): 16-row chunks of 1024 B per k-half.
    const int bsw  = (lane & 3) ^ ((lane >> 3) & 3);
    const int rowo = (lane >> 2);
    const int ldsA = wave * 4096 + lane * 16;
    const int ldsB = wave * 2048 + lane * 16;

    // fragment read: lane row r=lane&31, k-half q=lane>>5 (chunks 2q,2q+1);
    // swizzled slot p = r*4 + ((2q) ^ ((r>>1)&3)); partner chunk at ^16.
    const int r_  = lane & 31;
    const int q_  = lane >> 5;
    const int p16 = (r_ * 4 + ((2 * q_) ^ ((r_ >> 1) & 3))) * 16;
    const int aT0 = (wave >> 1) * 4;   // A regions aT0..aT0+3 (128 rows)
    const int bT0 = (wave & 1) * 2;    // B regions bT0..bT0+1 (64 rows)

    // id -> (bx, by); uniform per block (R22-verified, absmax 0).
    auto mapTile = [&](int id, int& bx, int& by) {
        if (id < 2048) { by = id >> 6; bx = 64 + (id & 63); }
        else {
            int p = id - 2048;
            int g = (int)((65.0f - sqrtf(4225.0f - 4.0f * (float)p)) * 0.5f);
            g = g < 0 ? 0 : (g > 31 ? 31 : g);
            while (g < 31 && (g + 1) * (65 - (g + 1)) <= p) ++g;
            while (g > 0 && g * (65 - g) > p) --g;
            by = g; bx = 2 * g + (p - g * (65 - g));
        }
    };

    // stage one BK=128 slice; addresses recomputed per call (no carried regs).
    auto stage = [&](int bx, int by, int k0) {
        const u8* gA0 = A + (size_t)(by * 256 + wave * 64 + rowo) * KDIM + bsw * 16 + k0;
        const u8* gB0 = B + (size_t)(bx * 128 + wave * 32 + rowo) * KDIM + bsw * 16 + k0;
        #pragma unroll
        for (int h = 0; h < 2; ++h) {
            const size_t kb = (size_t)h * 64;
            #pragma unroll
            for (int c = 0; c < 4; ++c)
                __builtin_amdgcn_global_load_lds(AS1(gA0 + kb + (size_t)c * 16 * KDIM),
                                                 AS3(&lA[h][ldsA + c * 1024]), 16, 0, 0);
            #pragma unroll
            for (int c = 0; c < 2; ++c)
                __builtin_amdgcn_global_load_lds(AS1(gB0 + kb + (size_t)c * 16 * KDIM),
                                                 AS3(&lB[h][ldsB + c * 1024]), 16, 0, 0);
        }
    };

    const float LOG2E10 = 14.4269504088896341f;

    int id = blockIdx.x;
    int bx, by;
    mapTile(id, bx, by);
    stage(bx, by, 0);                      // prologue prefetch: tile 0, k0=0

    while (true) {
        const bool pos = (bx < 64);
        const int  m0  = by * 256;
        const int  n0  = bx * 128;

        f32x16 accf[4][2];                 // scoped to this tile (no back-edge live)
        #pragma unroll
        for (int i = 0; i < 4; ++i)
            #pragma unroll
            for (int j = 0; j < 2; ++j)
                #pragma unroll
                for (int r = 0; r < 16; ++r)
                    accf[i][j][r] = 0.f;

        for (int k0 = 0; k0 < KDIM; k0 += 128) {   // BK=128: 4 iters
            if (k0) {
                __syncthreads();                   // prev reads done before overwrite
                stage(bx, by, k0);
            }
            __syncthreads();                       // vmcnt drain: both halves ready
            #pragma unroll
            for (int h = 0; h < 2; ++h) {          // 16 MFMAs between barrier pairs
                i32x8 af[4], bfr[2];
                #pragma unroll
                for (int mi = 0; mi < 4; ++mi) {
                    const int off = (aT0 + mi) * 2048 + p16;
                    *(i32x4*)&af[mi]       = *(const i32x4*)&lA[h][off];
                    *((i32x4*)&af[mi] + 1) = *(const i32x4*)&lA[h][off ^ 16];
                }
                #pragma unroll
                for (int ni = 0; ni < 2; ++ni) {
                    const int off = (bT0 + ni) * 2048 + p16;
                    *(i32x4*)&bfr[ni]       = *(const i32x4*)&lB[h][off];
                    *((i32x4*)&bfr[ni] + 1) = *(const i32x4*)&lB[h][off ^ 16];
                }
                #pragma unroll
                for (int mi = 0; mi < 4; ++mi)
                    #pragma unroll
                    for (int ni = 0; ni < 2; ++ni)
                        accf[mi][ni] = __builtin_amdgcn_mfma_scale_f32_32x32x64_f8f6f4(
                            af[mi], bfr[ni], accf[mi][ni],
                            0, 0,                 // cbsz=fp8(e4m3), blgp=fp8(e4m3)
                            0, 0x7f7f7f7f,        // scale_a: every byte = 2^0
                            0, 0x7f7f7f7f);       // scale_b
            }
        }

        __syncthreads();                           // last MFMA ds_reads done
        const int nid  = id + PBLOCKS;
        const bool more = (nid < NTILES);
        int nbx = bx, nby = by;
        if (more) {
            mapTile(nid, nbx, nby);
            stage(nbx, nby, 0);                    // hidden under epilogue VALU
        }

        // epilogue: exp(10*d) = exp2(d*10/ln2); diag-pair pos tiles skip rr==cc
        const bool diag = pos && ((bx >> 1) == by);
        float part = 0.f;
        if (diag) {
            #pragma unroll
            for (int mi = 0; mi < 4; ++mi)
                #pragma unroll
                for (int ni = 0; ni < 2; ++ni)
                    #pragma unroll
                    for (int r = 0; r < 16; ++r) {
                        // C/D 32x32: col=lane&31, row=(r&3)+8*(r>>2)+4*(lane>>5)
                        int rr = m0 + wm + mi * 32 + ((r & 3) + 8 * (r >> 2) + 4 * q_);
                        int cc = n0 + wn + ni * 32 + r_;
                        if (rr != cc) part += exp2f(accf[mi][ni][r] * LOG2E10);
                    }
        } else {
            #pragma unroll
            for (int mi = 0; mi < 4; ++mi)
                #pragma unroll
                for (int ni = 0; ni < 2; ++ni)
                    #pragma unroll
                    for (int r = 0; r < 16; ++r)
                        part += exp2f(accf[mi][ni][r] * LOG2E10);
        }

        #pragma unroll
        for (int off = 32; off >= 1; off >>= 1) part += __shfl_xor(part, off, 64);
        if (lane == 0) red[wave] = part;
        __syncthreads();                           // also drains prefetch (landed)
        if (tid == 0) {
            double s = (double)red[0] + (double)red[1] + (double)red[2] + (double)red[3];
            if (pos && !diag) s *= 2.0;            // stands in for skipped mirror
            atomicAdd(&acc[(pos ? 0 : 64) + (((unsigned)bx * 7 + (unsigned)by) & 63)], s);
        }
        __syncthreads();                           // red[] reusable next tile

        if (!more) break;
        id = nid; bx = nbx; by = nby;
    }
}

// --- Kernel 3: loss = log1p(neg/pos), pos += exact diagonal 8192*e^10.
// 128 threads, one global load each; LDS reduce then scalar finish.
__global__ __launch_bounds__(128) void finalize(const double* __restrict__ acc,
                                                float* __restrict__ out) {
    __shared__ double sp[128];
    const int t = threadIdx.x;
    sp[t] = acc[t];
    __syncthreads();
    if (t == 0) {
        double p = 0.0, n = 0.0;
        #pragma unroll
        for (int i = 0; i < 64; ++i) { p += sp[i]; n += sp[64 + i]; }
        p += 8192.0 * exp(10.0);
        out[0] = (float)log1p(n / p);
    }
}

extern "C" void kernel_launch(void* const* d_in, const int* in_sizes, int n_in,
                              void* d_out, int out_size, void* d_ws, size_t ws_size,
                              hipStream_t stream) {
    const float* zi = (const float*)d_in[0];
    const float* zj = (const float*)d_in[1];
    u8* nrm = (u8*)d_ws;                                      // [16384][512] fp8 = 8 MB
    double* acc = (double*)((char*)d_ws + (size_t)16384 * 512);

    nrm_kernel<<<4096, 256, 0, stream>>>(zi, zj, nrm, acc);
    gemm_exp_reduce<<<PBLOCKS, 256, 0, stream>>>(nrm, nrm, acc);
    finalize<<<1, 128, 0, stream>>>(acc, (float*)d_out);
}